// Round 18
// baseline (83487.958 us; speedup 1.0000x reference)
//
#include <hip/hip_runtime.h>
#include <hip/hip_bf16.h>
#include <math.h>

// Shapes: B=256, T=1024, F=128, D=256, UNITS=64. Inputs f32; out f32 [B,T,D].
//
// r17 PASSED with absmax = 0.0 (bit-exact vs the harness's np reference):
// the reference pipeline is XLA-CPU-f32: sequential ascending-k fmaf chains
// for both gemms, z = fmaf(shifted, u, h1), XLA EmitFastTanh. That
// arithmetic is FROZEN here — this round only reorganizes execution:
//  - full unroll + float4 LDS reads -> kc/rcf truly in VGPRs (r17 had them
//    in scratch: VGPR_Count=144, 33.5 GB FETCH from spill traffic)
//  - double-buffered LDS state -> ONE __syncthreads per step
//  - x prefetched one step ahead; store fire-and-forget.

__device__ __forceinline__ float xla_tanh(float x) {
    const float kClamp = 7.99881172180175781f;
    float xc = fminf(fmaxf(x, -kClamp), kClamp);
    float x2 = xc * xc;
    float num = -2.76076847742355e-16f;
    num = fmaf(x2, num, 2.00018790482477e-13f);
    num = fmaf(x2, num, -8.60467152213735e-11f);
    num = fmaf(x2, num, 5.12229709037114e-08f);
    num = fmaf(x2, num, 1.48572235717979e-05f);
    num = fmaf(x2, num, 6.37261928875436e-04f);
    num = fmaf(x2, num, 4.89352455891786e-03f);
    num = xc * num;
    float den = 1.19825839466702e-06f;
    den = fmaf(x2, den, 1.18534705686654e-04f);
    den = fmaf(x2, den, 2.26843463243900e-03f);
    den = fmaf(x2, den, 4.89352518554385e-03f);
    return (fabsf(x) < 0.0004f) ? x : (num / den);
}

__global__ __launch_bounds__(256, 1)
void lrs_fast(const float* __restrict__ x, const float* __restrict__ K,
              const float* __restrict__ R, const float* __restrict__ bias,
              float* __restrict__ out) {
    const int b = blockIdx.x;    // grid = 256, one batch row per block/CU
    const int d = threadIdx.x;   // 0..255, one output column per thread

    __shared__ __align__(16) float dxs[2][128];   // dx_t, double-buffered
    __shared__ __align__(16) float dh_s[2][256];  // h1 - h2
    __shared__ __align__(16) float h1_s[2][256];  // h1

    // weight columns resident in VGPRs (static indexing via full unroll)
    float kc[128];
#pragma unroll
    for (int j = 0; j < 128; ++j) kc[j] = K[j * 256 + d];
    float rcf[256];
#pragma unroll
    for (int i = 0; i < 256; ++i) rcf[i] = R[(size_t)i * 256 + d];
    const float bd = bias[d];    // zeros in this problem

    const float* xr   = x   + (size_t)b * (1024 * 128);
    float*       orow = out + (size_t)b * (1024 * 256);

    // prologue: t=0 state
    float x_cur = 0.0f;
    if (d < 128) {
        x_cur = xr[d];
        dxs[0][d] = x_cur;       // x0 - 0
    }
    dh_s[0][d] = 0.0f;
    h1_s[0][d] = 0.0f;
    float h1 = 0.0f;
    __syncthreads();

    for (int t = 0; t < 1024; ++t) {
        const int p = t & 1;

        // prefetch next x row early (latency hides under the FMA chains)
        float x_nxt = 0.0f;
        if (d < 128 && t < 1023) x_nxt = xr[(t + 1) * 128 + d];

        // mm1 = dx @ K[:,d] — sequential ascending-j fmaf chain (bit-exact;
        // float4 LDS reads only batch the loads, order of FMAs unchanged)
        float mm1 = 0.0f;
#pragma unroll
        for (int j = 0; j < 128; j += 4) {
            const float4 v = *reinterpret_cast<const float4*>(&dxs[p][j]);
            mm1 = fmaf(v.x, kc[j + 0], mm1);
            mm1 = fmaf(v.y, kc[j + 1], mm1);
            mm1 = fmaf(v.z, kc[j + 2], mm1);
            mm1 = fmaf(v.w, kc[j + 3], mm1);
        }

        // mm2 = dh @ R[:,d] — sequential ascending-i fmaf chain (bit-exact)
        float mm2 = 0.0f;
#pragma unroll
        for (int i = 0; i < 256; i += 4) {
            const float4 v = *reinterpret_cast<const float4*>(&dh_s[p][i]);
            mm2 = fmaf(v.x, rcf[i + 0], mm2);
            mm2 = fmaf(v.y, rcf[i + 1], mm2);
            mm2 = fmaf(v.z, rcf[i + 2], mm2);
            mm2 = fmaf(v.w, rcf[i + 3], mm2);
        }

        const float u  = (mm1 + mm2) + bd;
        const float sh = (d < 64) ? 1.0f : h1_s[p][d - 64];
        const float z  = fmaf(sh, u, h1);
        const float hn = xla_tanh(z);

        orow[t * 256 + d] = hn;              // fire-and-forget store

        // publish next-step state into the other buffer (no read race:
        // buffer p^1's step-(t-1) readers finished at the last barrier)
        dh_s[p ^ 1][d] = hn - h1;
        h1_s[p ^ 1][d] = hn;
        if (d < 128 && t < 1023) {
            dxs[p ^ 1][d] = x_nxt - x_cur;   // f32 sub (= ref)
            x_cur = x_nxt;
        }
        h1 = hn;
        __syncthreads();                     // single barrier per step
    }
}

extern "C" void kernel_launch(void* const* d_in, const int* in_sizes, int n_in,
                              void* d_out, int out_size, void* d_ws, size_t ws_size,
                              hipStream_t stream) {
    // Size-based mapping (element counts); fallback to dict order.
    const float* x = nullptr; const float* K = nullptr;
    const float* R = nullptr; const float* bias = nullptr;
    for (int i = 0; i < n_in; ++i) {
        switch (in_sizes[i]) {
            case 33554432: x    = (const float*)d_in[i]; break;
            case 32768:    K    = (const float*)d_in[i]; break;
            case 65536:    R    = (const float*)d_in[i]; break;
            case 256:      bias = (const float*)d_in[i]; break;
            default: break;
        }
    }
    if (!x || !K || !R || !bias) {
        x    = (const float*)d_in[0];
        K    = (const float*)d_in[1];
        R    = (const float*)d_in[2];
        bias = (const float*)d_in[3];
    }
    float* out = (float*)d_out;

    lrs_fast<<<256, 256, 0, stream>>>(x, K, R, bias, out);
}

// Round 19
// 2761.868 us; speedup vs baseline: 30.2288x; 30.2288x over previous
//
#include <hip/hip_runtime.h>
#include <hip/hip_bf16.h>
#include <math.h>

// Shapes: B=256, T=1024, F=128, D=256, UNITS=64. Inputs f32; out f32 [B,T,D].
//
// FROZEN arithmetic (r17, absmax=0.0 bit-exact): sequential ascending-k fmaf
// chains for both gemms, u=(mm1+mm2)+bias, z=fmaf(sh,u,h1), XLA EmitFastTanh.
// r18 lesson: allocator hard-caps at 256 VGPRs -> 384-float weight arrays
// spill; design within 256. This round:
//   Phase 1 (parallel): raw mm1 = dx@K chains -> in-place into d_out.
//   Phase 2 (recurrent): R split rcf[192] VGPR + rows 192..255 in LDS (64KB);
//   256-FMA chain order unchanged; 1 barrier/step; mm1 prefetched.

__device__ __forceinline__ float xla_tanh(float x) {
    const float kClamp = 7.99881172180175781f;
    float xc = fminf(fmaxf(x, -kClamp), kClamp);
    float x2 = xc * xc;
    float num = -2.76076847742355e-16f;
    num = fmaf(x2, num, 2.00018790482477e-13f);
    num = fmaf(x2, num, -8.60467152213735e-11f);
    num = fmaf(x2, num, 5.12229709037114e-08f);
    num = fmaf(x2, num, 1.48572235717979e-05f);
    num = fmaf(x2, num, 6.37261928875436e-04f);
    num = fmaf(x2, num, 4.89352455891786e-03f);
    num = xc * num;
    float den = 1.19825839466702e-06f;
    den = fmaf(x2, den, 1.18534705686654e-04f);
    den = fmaf(x2, den, 2.26843463243900e-03f);
    den = fmaf(x2, den, 4.89352518554385e-03f);
    return (fabsf(x) < 0.0004f) ? x : (num / den);
}

// ---------------- Phase 1: mm1[b,t,d] = dx_t @ K[:,d] (raw, no bias) -------
__global__ __launch_bounds__(256, 2)
void lrs_mm1(const float* __restrict__ x, const float* __restrict__ K,
             float* __restrict__ out) {
    const int d = threadIdx.x;
    float kc[128];
#pragma unroll
    for (int j = 0; j < 128; ++j) kc[j] = K[j * 256 + d];

    __shared__ __align__(16) float dx2[2][128];
    const int m0 = blockIdx.x * 256;          // grid 1024, 256 rows/block
    for (int mm = m0; mm < m0 + 256; mm += 2) {
        __syncthreads();                      // protect dx2 reuse
        if (d < 128) {                        // stage row mm
            const float xa  = x[(size_t)mm * 128 + d];
            const float xpa = (mm & 1023) ? x[(size_t)(mm - 1) * 128 + d] : 0.0f;
            dx2[0][d] = xa - xpa;             // f32 sub (= ref)
        } else {                              // stage row mm+1
            const int dd = d - 128;
            const float xb  = x[(size_t)(mm + 1) * 128 + dd];
            const float xpb = ((mm + 1) & 1023) ? x[(size_t)mm * 128 + dd] : 0.0f;
            dx2[1][dd] = xb - xpb;
        }
        __syncthreads();

        // two interleaved sequential ascending-j fmaf chains (ILP 2)
        float a0 = 0.0f, a1 = 0.0f;
#pragma unroll
        for (int j = 0; j < 128; j += 4) {
            const float4 v0 = *reinterpret_cast<const float4*>(&dx2[0][j]);
            const float4 v1 = *reinterpret_cast<const float4*>(&dx2[1][j]);
            a0 = fmaf(v0.x, kc[j + 0], a0);  a1 = fmaf(v1.x, kc[j + 0], a1);
            a0 = fmaf(v0.y, kc[j + 1], a0);  a1 = fmaf(v1.y, kc[j + 1], a1);
            a0 = fmaf(v0.z, kc[j + 2], a0);  a1 = fmaf(v1.z, kc[j + 2], a1);
            a0 = fmaf(v0.w, kc[j + 3], a0);  a1 = fmaf(v1.w, kc[j + 3], a1);
        }
        out[(size_t)mm * 256 + d]       = a0;   // raw mm1 (bias added in P2)
        out[(size_t)(mm + 1) * 256 + d] = a1;
    }
}

// ---------------- Phase 2: recurrence ---------------------------------------
#define NREG 192
__global__ __launch_bounds__(256, 1)
void lrs_rec(const float* __restrict__ R, const float* __restrict__ bias,
             float* __restrict__ out) {
    const int b = blockIdx.x;     // grid = 256, one batch row per block/CU
    const int d = threadIdx.x;    // one output column per thread

    __shared__ __align__(16) float dh_s[2][256];
    __shared__ __align__(16) float h1_s[2][256];
    __shared__ __align__(16) float rtail[64][256];   // R rows 192..255, 64 KB

    float rcf[NREG];              // R rows 0..191 for column d, in VGPRs
#pragma unroll
    for (int i = 0; i < NREG; ++i) rcf[i] = R[(size_t)i * 256 + d];
    for (int r = 0; r < 64; ++r)  rtail[r][d] = R[(size_t)(NREG + r) * 256 + d];
    const float bd = bias[d];     // zeros in this problem

    dh_s[0][d] = 0.0f;
    h1_s[0][d] = 0.0f;
    float h1 = 0.0f;
    __syncthreads();

    float* orow = out + (size_t)b * (1024 * 256);
    float u1 = orow[d];           // mm1 for t=0 (phase-1 result)

    for (int t = 0; t < 1024; ++t) {
        const int p = t & 1;
        // prefetch next step's mm1 (hides under the 256-FMA chain)
        const float u1n = (t < 1023) ? orow[(t + 1) * 256 + d] : 0.0f;

        // mm2 = dh @ R[:,d] — single sequential ascending-i fmaf chain;
        // i<192 from VGPRs, i>=192 from LDS (same order, bit-exact)
        float acc = 0.0f;
#pragma unroll
        for (int i = 0; i < NREG; i += 4) {
            const float4 v = *reinterpret_cast<const float4*>(&dh_s[p][i]);
            acc = fmaf(v.x, rcf[i + 0], acc);
            acc = fmaf(v.y, rcf[i + 1], acc);
            acc = fmaf(v.z, rcf[i + 2], acc);
            acc = fmaf(v.w, rcf[i + 3], acc);
        }
#pragma unroll
        for (int i = 0; i < 64; i += 4) {
            const float4 v = *reinterpret_cast<const float4*>(&dh_s[p][NREG + i]);
            acc = fmaf(v.x, rtail[i + 0][d], acc);
            acc = fmaf(v.y, rtail[i + 1][d], acc);
            acc = fmaf(v.z, rtail[i + 2][d], acc);
            acc = fmaf(v.w, rtail[i + 3][d], acc);
        }

        const float u  = (u1 + acc) + bd;               // (mm1 + mm2) + bias
        const float sh = (d < 64) ? 1.0f : h1_s[p][d - 64];
        const float z  = fmaf(sh, u, h1);
        const float hn = xla_tanh(z);

        orow[t * 256 + d] = hn;                         // overwrite mm1 slot

        dh_s[p ^ 1][d] = hn - h1;
        h1_s[p ^ 1][d] = hn;
        h1 = hn;
        u1 = u1n;
        __syncthreads();                                // single barrier/step
    }
}

extern "C" void kernel_launch(void* const* d_in, const int* in_sizes, int n_in,
                              void* d_out, int out_size, void* d_ws, size_t ws_size,
                              hipStream_t stream) {
    // Size-based mapping (element counts); fallback to dict order.
    const float* x = nullptr; const float* K = nullptr;
    const float* R = nullptr; const float* bias = nullptr;
    for (int i = 0; i < n_in; ++i) {
        switch (in_sizes[i]) {
            case 33554432: x    = (const float*)d_in[i]; break;
            case 32768:    K    = (const float*)d_in[i]; break;
            case 65536:    R    = (const float*)d_in[i]; break;
            case 256:      bias = (const float*)d_in[i]; break;
            default: break;
        }
    }
    if (!x || !K || !R || !bias) {
        x    = (const float*)d_in[0];
        K    = (const float*)d_in[1];
        R    = (const float*)d_in[2];
        bias = (const float*)d_in[3];
    }
    float* out = (float*)d_out;

    lrs_mm1<<<1024, 256, 0, stream>>>(x, K, out);
    lrs_rec<<<256, 256, 0, stream>>>(R, bias, out);
}

// Round 20
// 2578.626 us; speedup vs baseline: 32.3769x; 1.0711x over previous
//
#include <hip/hip_runtime.h>
#include <hip/hip_bf16.h>
#include <math.h>

// Shapes: B=256, T=1024, F=128, D=256, UNITS=64. Inputs f32; out f32 [B,T,D].
//
// FROZEN arithmetic (r17/r19, absmax=0.0 bit-exact): sequential ascending-k
// fmaf chains, u=(mm1+mm2)+bias, z=fmaf(sh,u,h1), XLA EmitFastTanh.
// r19 post-mortem: phase 2 = 5830 cyc/step, LDS-issue-bound (64 b128 dh
// broadcasts + 64 b32 rtail per thread per step on one LDS pipe).
// r20: dh[i] is wave-uniform -> load 256 dh as 4 b32/wave, feed the chain
// via v_readlane (SGPR operand). LDS instrs 128 -> ~70/thread/step; t-loop
// unrolled x2 for compile-time buffer offsets. Same FMAs, same order.

__device__ __forceinline__ float xla_tanh(float x) {
    const float kClamp = 7.99881172180175781f;
    float xc = fminf(fmaxf(x, -kClamp), kClamp);
    float x2 = xc * xc;
    float num = -2.76076847742355e-16f;
    num = fmaf(x2, num, 2.00018790482477e-13f);
    num = fmaf(x2, num, -8.60467152213735e-11f);
    num = fmaf(x2, num, 5.12229709037114e-08f);
    num = fmaf(x2, num, 1.48572235717979e-05f);
    num = fmaf(x2, num, 6.37261928875436e-04f);
    num = fmaf(x2, num, 4.89352455891786e-03f);
    num = xc * num;
    float den = 1.19825839466702e-06f;
    den = fmaf(x2, den, 1.18534705686654e-04f);
    den = fmaf(x2, den, 2.26843463243900e-03f);
    den = fmaf(x2, den, 4.89352518554385e-03f);
    return (fabsf(x) < 0.0004f) ? x : (num / den);
}

// ---------------- Phase 1: mm1[b,t,d] = dx_t @ K[:,d] (raw, no bias) -------
__global__ __launch_bounds__(256, 2)
void lrs_mm1(const float* __restrict__ x, const float* __restrict__ K,
             float* __restrict__ out) {
    const int d = threadIdx.x;
    float kc[128];
#pragma unroll
    for (int j = 0; j < 128; ++j) kc[j] = K[j * 256 + d];

    __shared__ __align__(16) float dx2[2][128];
    const int m0 = blockIdx.x * 256;          // grid 1024, 256 rows/block
    for (int mm = m0; mm < m0 + 256; mm += 2) {
        __syncthreads();                      // protect dx2 reuse
        if (d < 128) {                        // stage row mm
            const float xa  = x[(size_t)mm * 128 + d];
            const float xpa = (mm & 1023) ? x[(size_t)(mm - 1) * 128 + d] : 0.0f;
            dx2[0][d] = xa - xpa;             // f32 sub (= ref)
        } else {                              // stage row mm+1
            const int dd = d - 128;
            const float xb  = x[(size_t)(mm + 1) * 128 + dd];
            const float xpb = ((mm + 1) & 1023) ? x[(size_t)mm * 128 + dd] : 0.0f;
            dx2[1][dd] = xb - xpb;
        }
        __syncthreads();

        float a0 = 0.0f, a1 = 0.0f;
#pragma unroll
        for (int j = 0; j < 128; j += 4) {
            const float4 v0 = *reinterpret_cast<const float4*>(&dx2[0][j]);
            const float4 v1 = *reinterpret_cast<const float4*>(&dx2[1][j]);
            a0 = fmaf(v0.x, kc[j + 0], a0);  a1 = fmaf(v1.x, kc[j + 0], a1);
            a0 = fmaf(v0.y, kc[j + 1], a0);  a1 = fmaf(v1.y, kc[j + 1], a1);
            a0 = fmaf(v0.z, kc[j + 2], a0);  a1 = fmaf(v1.z, kc[j + 2], a1);
            a0 = fmaf(v0.w, kc[j + 3], a0);  a1 = fmaf(v1.w, kc[j + 3], a1);
        }
        out[(size_t)mm * 256 + d]       = a0;
        out[(size_t)(mm + 1) * 256 + d] = a1;
    }
}

// ---------------- Phase 2: recurrence ---------------------------------------
#define NREG 192
__device__ __forceinline__ float rdlane(float v, int l) {
    return __uint_as_float(__builtin_amdgcn_readlane(__float_as_uint(v), l));
}

__global__ __launch_bounds__(256, 1)
void lrs_rec(const float* __restrict__ R, const float* __restrict__ bias,
             float* __restrict__ out) {
    const int b    = blockIdx.x;   // grid = 256, one batch row per block/CU
    const int d    = threadIdx.x;  // one output column per thread
    const int lane = d & 63;

    __shared__ __align__(16) float dh0[256], dh1[256];
    __shared__ __align__(16) float h10[256], h11[256];
    __shared__ __align__(16) float rtail[64][256];   // R rows 192..255, 64 KB

    float rcf[NREG];               // R rows 0..191 for column d, in VGPRs
#pragma unroll
    for (int i = 0; i < NREG; ++i) rcf[i] = R[(size_t)i * 256 + d];
    for (int r = 0; r < 64; ++r)  rtail[r][d] = R[(size_t)(NREG + r) * 256 + d];
    const float bd = bias[d];      // zeros in this problem

    dh0[d] = 0.0f;
    h10[d] = 0.0f;
    float h1 = 0.0f;
    __syncthreads();

    float* orow = out + (size_t)b * (1024 * 256);
    float u1 = orow[d];            // mm1 for t=0 (phase-1 result)

    // One recurrence step with compile-time buffers. Chain arithmetic is the
    // exact r17 sequence: acc = fmaf(dh[i], R[i][d], acc), i ascending 0..255.
#define DO_STEP(DHC, H1C, DHN, H1N, T)                                        \
    {                                                                         \
        const float u1n = ((T) < 1023) ? orow[((T) + 1) * 256 + d] : 0.0f;    \
        const float sh  = (d < 64) ? 1.0f : H1C[d - 64];                      \
        const float c0 = DHC[lane],       c1 = DHC[64 + lane];                \
        const float c2 = DHC[128 + lane], c3 = DHC[192 + lane];               \
        float acc = 0.0f;                                                     \
        _Pragma("unroll")                                                     \
        for (int i = 0; i < 64; ++i)  acc = fmaf(rdlane(c0, i), rcf[i],        acc); \
        _Pragma("unroll")                                                     \
        for (int i = 0; i < 64; ++i)  acc = fmaf(rdlane(c1, i), rcf[64 + i],   acc); \
        _Pragma("unroll")                                                     \
        for (int i = 0; i < 64; ++i)  acc = fmaf(rdlane(c2, i), rcf[128 + i],  acc); \
        _Pragma("unroll")                                                     \
        for (int i = 0; i < 64; ++i)  acc = fmaf(rdlane(c3, i), rtail[i][d],   acc); \
        const float u  = (u1 + acc) + bd;                                     \
        const float z  = fmaf(sh, u, h1);                                     \
        const float hn = xla_tanh(z);                                         \
        orow[(T) * 256 + d] = hn;                                             \
        DHN[d] = hn - h1;                                                     \
        H1N[d] = hn;                                                          \
        h1 = hn; u1 = u1n;                                                    \
        __syncthreads();                                                      \
    }

    for (int t = 0; t < 1024; t += 2) {
        DO_STEP(dh0, h10, dh1, h11, t)
        DO_STEP(dh1, h11, dh0, h10, t + 1)
    }
#undef DO_STEP
}

extern "C" void kernel_launch(void* const* d_in, const int* in_sizes, int n_in,
                              void* d_out, int out_size, void* d_ws, size_t ws_size,
                              hipStream_t stream) {
    // Size-based mapping (element counts); fallback to dict order.
    const float* x = nullptr; const float* K = nullptr;
    const float* R = nullptr; const float* bias = nullptr;
    for (int i = 0; i < n_in; ++i) {
        switch (in_sizes[i]) {
            case 33554432: x    = (const float*)d_in[i]; break;
            case 32768:    K    = (const float*)d_in[i]; break;
            case 65536:    R    = (const float*)d_in[i]; break;
            case 256:      bias = (const float*)d_in[i]; break;
            default: break;
        }
    }
    if (!x || !K || !R || !bias) {
        x    = (const float*)d_in[0];
        K    = (const float*)d_in[1];
        R    = (const float*)d_in[2];
        bias = (const float*)d_in[3];
    }
    float* out = (float*)d_out;

    lrs_mm1<<<1024, 256, 0, stream>>>(x, K, out);
    lrs_rec<<<256, 256, 0, stream>>>(R, bias, out);
}

// Round 21
// 1536.068 us; speedup vs baseline: 54.3517x; 1.6787x over previous
//
#include <hip/hip_runtime.h>
#include <hip/hip_bf16.h>
#include <math.h>

// Shapes: B=256, T=1024, F=128, D=256, UNITS=64. Inputs f32; out f32 [B,T,D].
//
// FROZEN arithmetic (r17+, absmax=0.0 bit-exact): sequential ascending-k fmaf
// chains, u=(mm1+mm2)+bias, z=fmaf(sh,u,h1), XLA EmitFastTanh.
// r20 post-mortem: readlane emitted back-to-back with its FMA (lat+hazard
// ~10cyc each) + 64 rtail LDS reads/thread/step + AGPR demotion churn.
// r21: all 256 R values in the unified VGPR/AGPR file (no rtail LDS at all),
// readlanes prefetched in groups of 8, single-step rolling loop.

__device__ __forceinline__ float xla_tanh(float x) {
    const float kClamp = 7.99881172180175781f;
    float xc = fminf(fmaxf(x, -kClamp), kClamp);
    float x2 = xc * xc;
    float num = -2.76076847742355e-16f;
    num = fmaf(x2, num, 2.00018790482477e-13f);
    num = fmaf(x2, num, -8.60467152213735e-11f);
    num = fmaf(x2, num, 5.12229709037114e-08f);
    num = fmaf(x2, num, 1.48572235717979e-05f);
    num = fmaf(x2, num, 6.37261928875436e-04f);
    num = fmaf(x2, num, 4.89352455891786e-03f);
    num = xc * num;
    float den = 1.19825839466702e-06f;
    den = fmaf(x2, den, 1.18534705686654e-04f);
    den = fmaf(x2, den, 2.26843463243900e-03f);
    den = fmaf(x2, den, 4.89352518554385e-03f);
    return (fabsf(x) < 0.0004f) ? x : (num / den);
}

// ---------------- Phase 1: mm1[b,t,d] = dx_t @ K[:,d] (raw, no bias) -------
__global__ __launch_bounds__(256, 2)
void lrs_mm1(const float* __restrict__ x, const float* __restrict__ K,
             float* __restrict__ out) {
    const int d = threadIdx.x;
    float kc[128];
#pragma unroll
    for (int j = 0; j < 128; ++j) kc[j] = K[j * 256 + d];

    __shared__ __align__(16) float dx2[2][128];
    const int m0 = blockIdx.x * 256;          // grid 1024, 256 rows/block
    for (int mm = m0; mm < m0 + 256; mm += 2) {
        __syncthreads();                      // protect dx2 reuse
        if (d < 128) {                        // stage row mm
            const float xa  = x[(size_t)mm * 128 + d];
            const float xpa = (mm & 1023) ? x[(size_t)(mm - 1) * 128 + d] : 0.0f;
            dx2[0][d] = xa - xpa;             // f32 sub (= ref)
        } else {                              // stage row mm+1
            const int dd = d - 128;
            const float xb  = x[(size_t)(mm + 1) * 128 + dd];
            const float xpb = ((mm + 1) & 1023) ? x[(size_t)mm * 128 + dd] : 0.0f;
            dx2[1][dd] = xb - xpb;
        }
        __syncthreads();

        float a0 = 0.0f, a1 = 0.0f;
#pragma unroll
        for (int j = 0; j < 128; j += 4) {
            const float4 v0 = *reinterpret_cast<const float4*>(&dx2[0][j]);
            const float4 v1 = *reinterpret_cast<const float4*>(&dx2[1][j]);
            a0 = fmaf(v0.x, kc[j + 0], a0);  a1 = fmaf(v1.x, kc[j + 0], a1);
            a0 = fmaf(v0.y, kc[j + 1], a0);  a1 = fmaf(v1.y, kc[j + 1], a1);
            a0 = fmaf(v0.z, kc[j + 2], a0);  a1 = fmaf(v1.z, kc[j + 2], a1);
            a0 = fmaf(v0.w, kc[j + 3], a0);  a1 = fmaf(v1.w, kc[j + 3], a1);
        }
        out[(size_t)mm * 256 + d]       = a0;
        out[(size_t)(mm + 1) * 256 + d] = a1;
    }
}

// ---------------- Phase 2: recurrence ---------------------------------------
__device__ __forceinline__ float rdlane(float v, int l) {
    return __uint_as_float(__builtin_amdgcn_readlane(__float_as_uint(v), l));
}

__global__ __launch_bounds__(256, 1)
void lrs_rec(const float* __restrict__ R, const float* __restrict__ bias,
             float* __restrict__ out) {
    const int b    = blockIdx.x;   // grid = 256, one batch row per block/CU
    const int d    = threadIdx.x;  // one output column per thread
    const int lane = d & 63;

    __shared__ __align__(16) float dh0[256], dh1[256];
    __shared__ __align__(16) float h10[256], h11[256];

    // ALL of R[:,d] in the unified VGPR/AGPR file (r20: no scratch spill)
    float rcf[256];
#pragma unroll
    for (int i = 0; i < 256; ++i) rcf[i] = R[(size_t)i * 256 + d];
    const float bd = bias[d];      // zeros in this problem

    dh0[d] = 0.0f;
    h10[d] = 0.0f;
    float h1 = 0.0f;
    __syncthreads();

    float* orow = out + (size_t)b * (1024 * 256);
    float u1 = orow[d];            // mm1 for t=0 (phase-1 result)

    const float* dhc = dh0; float* dhn = dh1;
    const float* h1c = h10; float* h1n = h11;

    for (int t = 0; t < 1024; ++t) {
        // prefetch next step's mm1 (hidden under the chain)
        const float u1n = (t < 1023) ? orow[(t + 1) * 256 + d] : 0.0f;
        // multipliers: 4 per-lane LDS reads cover all 256 dh values per wave
        const float c0 = dhc[lane],       c1 = dhc[64 + lane];
        const float c2 = dhc[128 + lane], c3 = dhc[192 + lane];
        const float sh = (d < 64) ? 1.0f : h1c[d - 64];

        // mm2: single sequential ascending-i fmaf chain (bit-exact order).
        // Readlanes prefetched in groups of 8 -> scheduler hides RL latency
        // in the 4-cyc FMA dependency slack.
        float acc = 0.0f;
#define CHUNK(C, OFF)                                                         \
        _Pragma("unroll")                                                     \
        for (int g = 0; g < 8; ++g) {                                         \
            const int i0 = g * 8;                                             \
            const float m0 = rdlane(C, i0 + 0);                               \
            const float m1 = rdlane(C, i0 + 1);                               \
            const float m2 = rdlane(C, i0 + 2);                               \
            const float m3 = rdlane(C, i0 + 3);                               \
            const float m4 = rdlane(C, i0 + 4);                               \
            const float m5 = rdlane(C, i0 + 5);                               \
            const float m6 = rdlane(C, i0 + 6);                               \
            const float m7 = rdlane(C, i0 + 7);                               \
            acc = fmaf(m0, rcf[OFF + i0 + 0], acc);                           \
            acc = fmaf(m1, rcf[OFF + i0 + 1], acc);                           \
            acc = fmaf(m2, rcf[OFF + i0 + 2], acc);                           \
            acc = fmaf(m3, rcf[OFF + i0 + 3], acc);                           \
            acc = fmaf(m4, rcf[OFF + i0 + 4], acc);                           \
            acc = fmaf(m5, rcf[OFF + i0 + 5], acc);                           \
            acc = fmaf(m6, rcf[OFF + i0 + 6], acc);                           \
            acc = fmaf(m7, rcf[OFF + i0 + 7], acc);                           \
        }
        CHUNK(c0, 0)
        CHUNK(c1, 64)
        CHUNK(c2, 128)
        CHUNK(c3, 192)
#undef CHUNK

        const float u  = (u1 + acc) + bd;     // (mm1 + mm2) + bias
        const float z  = fmaf(sh, u, h1);
        const float hn = xla_tanh(z);

        orow[t * 256 + d] = hn;               // fire-and-forget store

        dhn[d] = hn - h1;                     // publish into the other buffer
        h1n[d] = hn;
        h1 = hn; u1 = u1n;

        // swap buffers
        const float* tp = dhc; dhc = dhn; dhn = (float*)tp;
        tp = h1c; h1c = h1n; h1n = (float*)tp;
        __syncthreads();                      // single barrier per step
    }
}

extern "C" void kernel_launch(void* const* d_in, const int* in_sizes, int n_in,
                              void* d_out, int out_size, void* d_ws, size_t ws_size,
                              hipStream_t stream) {
    // Size-based mapping (element counts); fallback to dict order.
    const float* x = nullptr; const float* K = nullptr;
    const float* R = nullptr; const float* bias = nullptr;
    for (int i = 0; i < n_in; ++i) {
        switch (in_sizes[i]) {
            case 33554432: x    = (const float*)d_in[i]; break;
            case 32768:    K    = (const float*)d_in[i]; break;
            case 65536:    R    = (const float*)d_in[i]; break;
            case 256:      bias = (const float*)d_in[i]; break;
            default: break;
        }
    }
    if (!x || !K || !R || !bias) {
        x    = (const float*)d_in[0];
        K    = (const float*)d_in[1];
        R    = (const float*)d_in[2];
        bias = (const float*)d_in[3];
    }
    float* out = (float*)d_out;

    lrs_mm1<<<1024, 256, 0, stream>>>(x, K, out);
    lrs_rec<<<256, 256, 0, stream>>>(R, bias, out);
}